// Round 1
// baseline (208.607 us; speedup 1.0000x reference)
//
#include <hip/hip_runtime.h>
#include <math.h>

#define H 1024
#define S 32768

// ws layout (floats):
//   [0, 1024)          v = W^T @ hidden
//   [1024, 1024+S)     scores
//   [1024+S, 1024+S+2) {max, sumexp}
#define WS_V      0
#define WS_SCORES 1024
#define WS_STATS  (1024 + S)

// ---------------------------------------------------------------------------
// v[h] = sum_d W[d*H + h] * hidden[d]
// grid (H/256, 16), block 256. Each block: 256 h-columns x 64 d-rows partial.
// ---------------------------------------------------------------------------
__global__ __launch_bounds__(256) void matvec_wt_h(const float* __restrict__ W,
                                                   const float* __restrict__ hidden,
                                                   float* __restrict__ v) {
    const int h  = blockIdx.x * 256 + threadIdx.x;
    const int d0 = blockIdx.y * 64;
    float acc = 0.f;
#pragma unroll 8
    for (int i = 0; i < 64; ++i) {
        const int d = d0 + i;
        acc += W[(size_t)d * H + h] * hidden[d];   // coalesced across h; hidden[d] scalar-load
    }
    atomicAdd(&v[h], acc);
}

// ---------------------------------------------------------------------------
// scores[row] = dot(enc[row, :], v)   — one wave (64 lanes) per row.
// Row = 1024 floats = 256 float4. Lane l handles float4 indices l + 64k, k=0..3.
// v fragment is row-invariant -> held in 16 registers per lane.
// ---------------------------------------------------------------------------
__global__ __launch_bounds__(256) void scores_kernel(const float* __restrict__ enc,
                                                     const float* __restrict__ v,
                                                     float* __restrict__ scores) {
    const int lane = threadIdx.x & 63;
    const int wave = threadIdx.x >> 6;
    const int wavesPerBlock = blockDim.x >> 6;                 // 4
    const int globalWave = blockIdx.x * wavesPerBlock + wave;
    const int numWaves   = gridDim.x * wavesPerBlock;

    const float4* v4 = (const float4*)v;
    float4 vf[4];
#pragma unroll
    for (int k = 0; k < 4; ++k) vf[k] = v4[lane + 64 * k];     // L2/L3-cached after first block

    for (int row = globalWave; row < S; row += numWaves) {
        const float4* e4 = (const float4*)(enc + (size_t)row * H);
        float acc = 0.f;
#pragma unroll
        for (int k = 0; k < 4; ++k) {
            const float4 e = e4[lane + 64 * k];                // 16B/lane, 1KiB/wave/instr
            acc += e.x * vf[k].x + e.y * vf[k].y + e.z * vf[k].z + e.w * vf[k].w;
        }
#pragma unroll
        for (int off = 32; off > 0; off >>= 1)
            acc += __shfl_xor(acc, off, 64);
        if (lane == 0) scores[row] = acc;
    }
}

// ---------------------------------------------------------------------------
// Single block (1024 threads): stats[0]=max(scores), stats[1]=sum(exp(s-max)).
// Each thread owns 32 scores in registers.
// ---------------------------------------------------------------------------
__global__ __launch_bounds__(1024) void softmax_stats(const float* __restrict__ scores,
                                                      float* __restrict__ stats) {
    __shared__ float redm[16];
    __shared__ float reds[16];
    const int tid  = threadIdx.x;
    const int lane = tid & 63;
    const int wv   = tid >> 6;

    float local[32];
    float m = -INFINITY;
#pragma unroll
    for (int i = 0; i < 32; ++i) {
        local[i] = scores[tid + i * 1024];                     // coalesced
        m = fmaxf(m, local[i]);
    }
#pragma unroll
    for (int off = 32; off > 0; off >>= 1)
        m = fmaxf(m, __shfl_xor(m, off, 64));
    if (lane == 0) redm[wv] = m;
    __syncthreads();
    float bm = redm[0];
#pragma unroll
    for (int i = 1; i < 16; ++i) bm = fmaxf(bm, redm[i]);

    float s = 0.f;
#pragma unroll
    for (int i = 0; i < 32; ++i) s += __expf(local[i] - bm);
#pragma unroll
    for (int off = 32; off > 0; off >>= 1)
        s += __shfl_xor(s, off, 64);
    if (lane == 0) reds[wv] = s;
    __syncthreads();
    if (tid == 0) {
        float ts = 0.f;
#pragma unroll
        for (int i = 0; i < 16; ++i) ts += reds[i];
        stats[0] = bm;
        stats[1] = ts;
    }
}

// ---------------------------------------------------------------------------
// out[i] = exp(scores[i] - max) / sumexp
// ---------------------------------------------------------------------------
__global__ __launch_bounds__(256) void normalize_kernel(const float* __restrict__ scores,
                                                        const float* __restrict__ stats,
                                                        float* __restrict__ out) {
    const int i = blockIdx.x * 256 + threadIdx.x;
    const float m  = stats[0];
    const float rs = 1.0f / stats[1];
    out[i] = __expf(scores[i] - m) * rs;
}

extern "C" void kernel_launch(void* const* d_in, const int* in_sizes, int n_in,
                              void* d_out, int out_size, void* d_ws, size_t ws_size,
                              hipStream_t stream) {
    const float* hidden = (const float*)d_in[0];   // [H]
    const float* enc    = (const float*)d_in[1];   // [S, H]
    const float* W      = (const float*)d_in[2];   // [H, H]
    // d_in[3] = b — unused: b·hidden is a uniform shift, softmax is shift-invariant.
    float* out = (float*)d_out;                    // [S] fp32

    float* ws     = (float*)d_ws;
    float* v      = ws + WS_V;
    float* scores = ws + WS_SCORES;
    float* stats  = ws + WS_STATS;

    // zero the atomicAdd accumulator (ws is poisoned 0xAA each call)
    hipMemsetAsync(v, 0, H * sizeof(float), stream);

    dim3 g1(H / 256, 16);
    matvec_wt_h<<<g1, 256, 0, stream>>>(W, hidden, v);

    scores_kernel<<<1024, 256, 0, stream>>>(enc, v, scores);

    softmax_stats<<<1, 1024, 0, stream>>>(scores, stats);

    normalize_kernel<<<S / 256, 256, 0, stream>>>(scores, stats, out);
}

// Round 3
// 207.726 us; speedup vs baseline: 1.0042x; 1.0042x over previous
//
#include <hip/hip_runtime.h>
#include <math.h>

#define H 1024
#define S 32768
#define NPART 16          // d-partials for the W^T @ hidden matvec

// ws layout (floats):
//   [0, 16384)            partial[p][h]  p<16, h<1024
//   [16384, 16384+S)      scores
//   [49152, 50176)        pm (per-block softmax max)
//   [50176, 51200)        ps (per-block softmax sumexp)
#define WS_PART   0
#define WS_SCORES 16384
#define WS_PM     (16384 + S)
#define WS_PS     (16384 + S + 1024)

// ---------------------------------------------------------------------------
// K1: partial[by][h] = sum_{d in by-chunk of 64} W[d][h] * hidden[d]
// grid (4, 16), block 256. No atomics, no memset needed.
// ---------------------------------------------------------------------------
__global__ __launch_bounds__(256) void matvec_partial(const float* __restrict__ W,
                                                      const float* __restrict__ hidden,
                                                      float* __restrict__ ws) {
    float* part = ws + WS_PART;
    const int h  = blockIdx.x * 256 + threadIdx.x;
    const int by = blockIdx.y;
    const int d0 = by * 64;
    float acc = 0.f;
#pragma unroll 8
    for (int i = 0; i < 64; ++i) {
        const int d = d0 + i;
        acc += W[(size_t)d * H + h] * hidden[d];   // 1 KB contiguous per d
    }
    part[by * H + h] = acc;
}

// ---------------------------------------------------------------------------
// K2: per-row scores + per-block online softmax partials.
// 1024 blocks x 256 threads; wave w of block b owns rows (b*4+w)*8 .. +8.
// v is rebuilt once per block into LDS from the 16 partials (L2-resident).
// ---------------------------------------------------------------------------
__global__ __launch_bounds__(256) void scores_partial(const float* __restrict__ enc,
                                                      float* __restrict__ ws) {
    float* part   = ws + WS_PART;
    float* scores = ws + WS_SCORES;
    float* pm     = ws + WS_PM;
    float* ps     = ws + WS_PS;

    const int tid  = threadIdx.x;
    const int lane = tid & 63;
    const int wv   = tid >> 6;
    const int blk  = blockIdx.x;

    // --- rebuild v into LDS: thread t owns float4 index t ---
    __shared__ float vsh[H];
    {
        const float4* p4 = (const float4*)part;
        float4 a = make_float4(0.f, 0.f, 0.f, 0.f);
#pragma unroll
        for (int p = 0; p < NPART; ++p) {
            const float4 w = p4[p * (H / 4) + tid];
            a.x += w.x; a.y += w.y; a.z += w.z; a.w += w.w;
        }
        ((float4*)vsh)[tid] = a;
    }
    __syncthreads();

    const float4* v4 = (const float4*)vsh;
    float4 vf[4];
#pragma unroll
    for (int k = 0; k < 4; ++k) vf[k] = v4[lane + 64 * k];

    // --- 8 rows per wave, online softmax ---
    const int gw = blk * 4 + wv;
    float mw = -INFINITY, sw = 0.f;
#pragma unroll
    for (int it = 0; it < 8; ++it) {
        const int row = gw * 8 + it;
        const float4* e4 = (const float4*)(enc + (size_t)row * H);
        float a = 0.f;
#pragma unroll
        for (int k = 0; k < 4; ++k) {
            const float4 e = e4[lane + 64 * k];      // 16 B/lane, coalesced
            a += e.x * vf[k].x + e.y * vf[k].y + e.z * vf[k].z + e.w * vf[k].w;
        }
#pragma unroll
        for (int off = 32; off > 0; off >>= 1)
            a += __shfl_xor(a, off, 64);
        if (lane == 0) scores[row] = a;
        const float nm = fmaxf(mw, a);
        sw = sw * __expf(mw - nm) + __expf(a - nm);
        mw = nm;
    }

    __shared__ float sm[4], ss[4];
    if (lane == 0) { sm[wv] = mw; ss[wv] = sw; }
    __syncthreads();
    if (tid == 0) {
        float m = sm[0], s = ss[0];
#pragma unroll
        for (int i = 1; i < 4; ++i) {
            const float nm = fmaxf(m, sm[i]);
            s = s * __expf(m - nm) + ss[i] * __expf(sm[i] - nm);
            m = nm;
        }
        pm[blk] = m; ps[blk] = s;
    }
}

// ---------------------------------------------------------------------------
// K3: every block redundantly combines the 1024 (m,s) pairs, then
// normalizes its 256 scores. grid 128 blocks x 256 threads.
// ---------------------------------------------------------------------------
__global__ __launch_bounds__(256) void finalize(const float* __restrict__ ws,
                                                float* __restrict__ out) {
    const float* scores = ws + WS_SCORES;
    const float* pm     = ws + WS_PM;
    const float* ps     = ws + WS_PS;

    const int tid  = threadIdx.x;
    const int lane = tid & 63;
    const int wv   = tid >> 6;

    // thread-local combine of 4 pairs
    float m = -INFINITY, s = 0.f;
#pragma unroll
    for (int i = 0; i < 4; ++i) {
        const int idx = tid + i * 256;
        const float om = pm[idx], os = ps[idx];
        const float nm = fmaxf(m, om);
        s = s * __expf(m - nm) + os * __expf(om - nm);
        m = nm;
    }
    // wave combine
#pragma unroll
    for (int off = 32; off > 0; off >>= 1) {
        const float om = __shfl_xor(m, off, 64);
        const float os = __shfl_xor(s, off, 64);
        const float nm = fmaxf(m, om);
        s = s * __expf(m - nm) + os * __expf(om - nm);
        m = nm;
    }
    __shared__ float sm[4], ss[4];
    if (lane == 0) { sm[wv] = m; ss[wv] = s; }
    __syncthreads();
    float M = sm[0], Ssum = ss[0];
#pragma unroll
    for (int i = 1; i < 4; ++i) {
        const float nm = fmaxf(M, sm[i]);
        Ssum = Ssum * __expf(M - nm) + ss[i] * __expf(sm[i] - nm);
        M = nm;
    }
    const float rs = 1.0f / Ssum;

    const int i = blockIdx.x * 256 + tid;
    out[i] = __expf(scores[i] - M) * rs;
}

extern "C" void kernel_launch(void* const* d_in, const int* in_sizes, int n_in,
                              void* d_out, int out_size, void* d_ws, size_t ws_size,
                              hipStream_t stream) {
    const float* hidden = (const float*)d_in[0];   // [H]
    const float* enc    = (const float*)d_in[1];   // [S, H]
    const float* W      = (const float*)d_in[2];   // [H, H]
    // d_in[3] = b — unused: b·hidden is a uniform softmax shift (cancels exactly).
    float* out = (float*)d_out;                    // [S] fp32
    float* ws  = (float*)d_ws;

    matvec_partial<<<dim3(H / 256, NPART), 256, 0, stream>>>(W, hidden, ws);
    scores_partial<<<1024, 256, 0, stream>>>(enc, ws);
    finalize<<<S / 256, 256, 0, stream>>>(ws, out);
}